// Round 5
// baseline (84.845 us; speedup 1.0000x reference)
//
#include <hip/hip_runtime.h>
#include <math.h>

#define EPSF 1e-7f
// 1/(1 - SIGMA - ln(1 - SIGMA)) with SIGMA = 0.5
#define REP_INV (1.0f / 1.19314718055994530942f)
#define NBUCK 1024

// Box record: 8 floats (32B aligned): x0, y0, x1p(=x1+1), y1p(=y1+1), area(+1 conv), pad*3

// ---------------------------------------------------------------------------
// prep: xywh -> records for gt and pre; bucket id (x-center quantized) per pred.
// ---------------------------------------------------------------------------
__global__ __launch_bounds__(256) void prep_kernel(
    const float* __restrict__ gt, const float* __restrict__ pre,
    float* __restrict__ gB, float* __restrict__ pB, int* __restrict__ bucketId,
    int M, int N, float bscale)
{
    int i = blockIdx.x * 256 + threadIdx.x;
    if (i < M) {
        float x = gt[i * 4 + 0], y = gt[i * 4 + 1], w = gt[i * 4 + 2], h = gt[i * 4 + 3];
        float x0 = x - w * 0.5f, y0 = y - h * 0.5f;
        float x1p = x + w * 0.5f + 1.0f, y1p = y + h * 0.5f + 1.0f;
        *(float4*)(gB + (size_t)i * 8) = make_float4(x0, y0, x1p, y1p);
        gB[(size_t)i * 8 + 4] = (x1p - x0) * (y1p - y0);
    }
    if (i < N) {
        float x = pre[i * 4 + 0], y = pre[i * 4 + 1], w = pre[i * 4 + 2], h = pre[i * 4 + 3];
        float x0 = x - w * 0.5f, y0 = y - h * 0.5f;
        float x1p = x + w * 0.5f + 1.0f, y1p = y + h * 0.5f + 1.0f;
        *(float4*)(pB + (size_t)i * 8) = make_float4(x0, y0, x1p, y1p);
        pB[(size_t)i * 8 + 4] = (x1p - x0) * (y1p - y0);
        int b = (int)(x * bscale);
        bucketId[i] = min(max(b, 0), NBUCK - 1);
    }
}

// ---------------------------------------------------------------------------
// sort: single block, counting sort of preds by x-bucket; then per-128-box
// tile x-bounds (min x0, max x1p). Sum over unordered pairs is permutation-
// invariant, so reordering is exact up to FP summation order.
// ---------------------------------------------------------------------------
__global__ __launch_bounds__(1024) void sort_kernel(
    const float* __restrict__ pB, const int* __restrict__ bucketId,
    float* __restrict__ sB, float* __restrict__ tb, int N)
{
    __shared__ int hist[NBUCK];
    __shared__ int scanb[NBUCK];
    __shared__ float hmin[128], hmax[128];
    int t = threadIdx.x;
    hist[t] = 0;
    __syncthreads();

    int nc = (N + 1023) >> 10;
    for (int k = 0; k < nc; ++k) {
        int i = k * 1024 + t;
        if (i < N) atomicAdd(&hist[bucketId[i]], 1);
    }
    __syncthreads();

    // Hillis-Steele inclusive scan over NBUCK
    int own = hist[t];
    scanb[t] = own;
    __syncthreads();
    for (int off = 1; off < NBUCK; off <<= 1) {
        int u = (t >= off) ? scanb[t - off] : 0;
        __syncthreads();
        scanb[t] += u;
        __syncthreads();
    }
    hist[t] = scanb[t] - own;   // exclusive offset, used as running cursor
    __syncthreads();

    // scatter (within-bucket order nondeterministic; FP-sum benign)
    for (int k = 0; k < nc; ++k) {
        int i = k * 1024 + t;
        if (i < N) {
            int dst = atomicAdd(&hist[bucketId[i]], 1);
            float4 r = *(const float4*)(pB + (size_t)i * 8);
            float  a = pB[(size_t)i * 8 + 4];
            *(float4*)(sB + (size_t)dst * 8) = r;
            sB[(size_t)dst * 8 + 4] = a;
        }
    }
    __threadfence();
    __syncthreads();

    // per-64-box half-tile bounds, then combine to 128-box tiles
    if (t < 128) { hmin[t] = 3.4e38f; hmax[t] = -3.4e38f; }
    __syncthreads();
    for (int k = 0; k < nc; ++k) {
        int i = k * 1024 + t;
        float x0 = 3.4e38f, x1p = -3.4e38f;
        if (i < N) { x0 = sB[(size_t)i * 8]; x1p = sB[(size_t)i * 8 + 2]; }
        for (int off = 32; off > 0; off >>= 1) {
            x0  = fminf(x0,  __shfl_xor(x0, off));
            x1p = fmaxf(x1p, __shfl_xor(x1p, off));
        }
        int halfIdx = (k * 1024 + (t & ~63)) >> 6;
        if ((t & 63) == 0 && halfIdx < 128) { hmin[halfIdx] = x0; hmax[halfIdx] = x1p; }
    }
    __syncthreads();
    int ntile = (N + 127) >> 7;
    int nh = (N + 63) >> 6;
    if (t < ntile) {
        float mn = hmin[2 * t], mx = hmax[2 * t];
        if (2 * t + 1 < nh) { mn = fminf(mn, hmin[2 * t + 1]); mx = fmaxf(mx, hmax[2 * t + 1]); }
        tb[2 * t] = mn;
        tb[2 * t + 1] = mx;
    }
}

// ---------------------------------------------------------------------------
// attr + repgt: one wave per prediction, 2 preds per wave (grid-stride).
// Single-pass per-lane top-2 + butterfly merge; (value, min-index) tie-break
// reproduces jnp.argmax first-occurrence semantics for both passes.
// ---------------------------------------------------------------------------
__global__ __launch_bounds__(256) void attr_repgt_kernel(
    const float* __restrict__ gB, const float* __restrict__ pB,
    double* __restrict__ attrP, double* __restrict__ repgtP, int M, int N)
{
    __shared__ float4 gs4[512];
    __shared__ float  gsA[512];
    __shared__ double red[8];
    int t = threadIdx.x;
    for (int k = t; k < M; k += 256) {
        gs4[k] = *(const float4*)(gB + (size_t)k * 8);
        gsA[k] = gB[(size_t)k * 8 + 4];
    }
    if (t < 8) red[t] = 0.0;
    __syncthreads();

    int wave = t >> 6, lane = t & 63;
    int wgid = blockIdx.x * 4 + wave;
    int nw = gridDim.x * 4;
    double sAcc = 0.0, rAcc = 0.0;

    for (int n = wgid; n < N; n += nw) {
        float4 p = *(const float4*)(pB + (size_t)n * 8);
        float  pa = pB[(size_t)n * 8 + 4];

        float b1 = -1.0f, b2 = -1.0f; int i1 = 0, i2 = 0;
        for (int m = lane; m < M; m += 64) {
            float4 g = gs4[m]; float ga = gsA[m];
            float w = fmaxf(fminf(g.z, p.z) - fmaxf(g.x, p.x), 0.0f);
            float h = fmaxf(fminf(g.w, p.w) - fmaxf(g.y, p.y), 0.0f);
            float ov = w * h;
            float v = ov * __builtin_amdgcn_rcpf(fmaxf(ga + pa - ov, EPSF));
            v = fminf(fmaxf(v, EPSF), 1.0f);
            if (v > b1)      { b2 = b1; i2 = i1; b1 = v; i1 = m; }
            else if (v > b2) { b2 = v; i2 = m; }
        }
        // merge pass 1: global (B1, I1)
        float B1 = b1; int I1 = i1;
        for (int off = 32; off > 0; off >>= 1) {
            float bv = __shfl_xor(B1, off);
            int   bi = __shfl_xor(I1, off);
            if (bv > B1 || (bv == B1 && bi < I1)) { B1 = bv; I1 = bi; }
        }
        // merge pass 2: exclude index I1
        float cb = (i1 == I1) ? b2 : b1;
        int   ci = (i1 == I1) ? i2 : i1;
        float B2 = cb; int I2 = ci;
        for (int off = 32; off > 0; off >>= 1) {
            float bv = __shfl_xor(B2, off);
            int   bi = __shfl_xor(I2, off);
            if (bv > B2 || (bv == B2 && bi < I2)) { B2 = bv; I2 = bi; }
        }

        if (lane == 0) {
            // attr: smooth-l1 (beta=1) vs g[I1]; (x1p-gx1p)==(x1-gx1)
            float4 a = gs4[I1];
            float s = 0.0f, d;
            d = fabsf(p.x - a.x); s += (d < 1.0f) ? 0.5f * d * d : d - 0.5f;
            d = fabsf(p.y - a.y); s += (d < 1.0f) ? 0.5f * d * d : d - 0.5f;
            d = fabsf(p.z - a.z); s += (d < 1.0f) ? 0.5f * d * d : d - 0.5f;
            d = fabsf(p.w - a.w); s += (d < 1.0f) ? 0.5f * d * d : d - 0.5f;

            // repgt: IoG (no +1 convention) vs g[I2]; raw x1 = x1p - 1
            float4 rg = gs4[I2];
            float lx = fmaxf(p.x, rg.x), ly = fmaxf(p.y, rg.y);
            float rbx = fminf(p.z, rg.z) - 1.0f, rby = fminf(p.w, rg.w) - 1.0f;
            float w = fmaxf(rbx - lx, 0.0f), h = fmaxf(rby - ly, 0.0f);
            float inter = w * h;
            float garea = fabsf(rg.z - 1.0f - rg.x) * fabsf(rg.w - 1.0f - rg.y);
            float iog = inter / garea;
            float rep;
            if (iog > 0.5f) rep = (iog - 0.5f) * REP_INV;
            else            rep = -logf(fmaxf(1.0f - iog, EPSF));
            sAcc += (double)s;
            rAcc += (double)rep;
        }
    }
    if (lane == 0) { red[wave] = sAcc; red[4 + wave] = rAcc; }
    __syncthreads();
    if (t == 0) {
        attrP[blockIdx.x]  = red[0] + red[1] + red[2] + red[3];
        repgtP[blockIdx.x] = red[4] + red[5] + red[6] + red[7];
    }
}

// ---------------------------------------------------------------------------
// repbox on SORTED preds: grid-stride over upper-tri 128x128 tiles.
// Tile-level skip via x-bounds (sorted by x => most tiles disjoint).
// Zero-overlap pairs contribute 0 (true value -log(1-EPS) ~ 1e-7; total
// final-scalar error ~5e-8 << threshold).
// ---------------------------------------------------------------------------
__global__ __launch_bounds__(256) void repbox_kernel(
    const float* __restrict__ sB, const float* __restrict__ tb,
    double* __restrict__ boxP, int N, int nt, int nTri)
{
    __shared__ float4 rows4[128];
    __shared__ float  rowsA[128];
    __shared__ double red[4];
    int t = threadIdx.x, wv = t >> 6, lane = t & 63;
    double acc = 0.0;

    for (int s = blockIdx.x; s < nTri; s += gridDim.x) {
        // decode triangular index s -> (bi, bj), bi <= bj
        float a = 2.0f * (float)nt + 1.0f;
        int bi = (int)((a - sqrtf(a * a - 8.0f * (float)s)) * 0.5f);
        if (bi < 0) bi = 0;
        if (bi > nt - 1) bi = nt - 1;
        while (bi > 0 && (long long)bi * nt - (long long)bi * (bi - 1) / 2 > s) --bi;
        while ((long long)(bi + 1) * nt - (long long)(bi + 1) * bi / 2 <= s) ++bi;
        long long rowoff = (long long)bi * nt - (long long)bi * (bi - 1) / 2;
        int bj = bi + (int)(s - rowoff);

        // x-disjoint tile skip (uniform branch: same scalars for all threads)
        float rmin = tb[2 * bi], rmax = tb[2 * bi + 1];
        float cmin = tb[2 * bj], cmax = tb[2 * bj + 1];
        if (cmin >= rmax || rmin >= cmax) continue;

        int rbase = bi * 128, cbase = bj * 128;
        __syncthreads();   // protect LDS reuse across tiles
        if (t < 128) {
            int rg = rbase + t;
            int rc = (rg < N) ? rg : 0;
            rows4[t] = *(const float4*)(sB + (size_t)rc * 8);
            rowsA[t] = sB[(size_t)rc * 8 + 4];
        }
        int j0 = cbase + lane, j1 = j0 + 64;
        int j0c = (j0 < N) ? j0 : 0;
        int j1c = (j1 < N) ? j1 : 0;
        float4 c0 = *(const float4*)(sB + (size_t)j0c * 8);
        float  c0a = sB[(size_t)j0c * 8 + 4];
        float4 c1 = *(const float4*)(sB + (size_t)j1c * 8);
        float  c1a = sB[(size_t)j1c * 8 + 4];
        __syncthreads();

        float sum = 0.0f;
        int r0 = wv * 32;
        bool interior = (bi < bj) && (rbase + 128 <= N) && (cbase + 128 <= N);

        if (interior) {
            #pragma unroll 4
            for (int rr = 0; rr < 32; ++rr) {
                int r = r0 + rr;
                float4 rb = rows4[r]; float ra = rowsA[r];
                float w0 = fmaxf(fminf(rb.z, c0.z) - fmaxf(rb.x, c0.x), 0.0f);
                float h0 = fmaxf(fminf(rb.w, c0.w) - fmaxf(rb.y, c0.y), 0.0f);
                float ov0 = w0 * h0;
                float w1 = fmaxf(fminf(rb.z, c1.z) - fmaxf(rb.x, c1.x), 0.0f);
                float h1 = fmaxf(fminf(rb.w, c1.w) - fmaxf(rb.y, c1.y), 0.0f);
                float ov1 = w1 * h1;
                if (__any(ov0 + ov1 > 0.0f)) {
                    float v0 = ov0 * __builtin_amdgcn_rcpf(ra + c0a - ov0);
                    float t0 = (v0 > 0.5f) ? (v0 - 0.5f) * REP_INV
                                           : 0.0f - __logf(fmaxf(1.0f - v0, EPSF));
                    float v1 = ov1 * __builtin_amdgcn_rcpf(ra + c1a - ov1);
                    float t1 = (v1 > 0.5f) ? (v1 - 0.5f) * REP_INV
                                           : 0.0f - __logf(fmaxf(1.0f - v1, EPSF));
                    sum += t0 + t1;
                }
            }
        } else {
            #pragma unroll 4
            for (int rr = 0; rr < 32; ++rr) {
                int r = r0 + rr;
                int ig = rbase + r;
                float4 rb = rows4[r]; float ra = rowsA[r];
                float w0 = fmaxf(fminf(rb.z, c0.z) - fmaxf(rb.x, c0.x), 0.0f);
                float h0 = fmaxf(fminf(rb.w, c0.w) - fmaxf(rb.y, c0.y), 0.0f);
                float ov0 = w0 * h0;
                float w1 = fmaxf(fminf(rb.z, c1.z) - fmaxf(rb.x, c1.x), 0.0f);
                float h1 = fmaxf(fminf(rb.w, c1.w) - fmaxf(rb.y, c1.y), 0.0f);
                float ov1 = w1 * h1;
                bool valid0 = (j0 > ig) && (j0 < N) && (ig < N);
                bool valid1 = (j1 > ig) && (j1 < N) && (ig < N);
                if (__any(ov0 + ov1 > 0.0f)) {
                    float v0 = ov0 * __builtin_amdgcn_rcpf(ra + c0a - ov0);
                    float t0 = (v0 > 0.5f) ? (v0 - 0.5f) * REP_INV
                                           : 0.0f - __logf(fmaxf(1.0f - v0, EPSF));
                    float v1 = ov1 * __builtin_amdgcn_rcpf(ra + c1a - ov1);
                    float t1 = (v1 > 0.5f) ? (v1 - 0.5f) * REP_INV
                                           : 0.0f - __logf(fmaxf(1.0f - v1, EPSF));
                    if (valid0) sum += t0;
                    if (valid1) sum += t1;
                }
            }
        }

        for (int off = 32; off > 0; off >>= 1) sum += __shfl_down(sum, off);
        if (lane == 0) red[wv] = (double)sum;
        __syncthreads();
        if (t == 0) acc += red[0] + red[1] + red[2] + red[3];
    }
    if (t == 0) boxP[blockIdx.x] = acc;
}

// ---------------------------------------------------------------------------
// finalize: one block sums the partial arrays (L2-resident).
// ---------------------------------------------------------------------------
__device__ __forceinline__ double block_sum(const double* p, int n, int t,
                                            double* sred) {
    double s = 0.0;
    for (int k = t; k < n; k += 256) s += p[k];
    for (int off = 32; off > 0; off >>= 1) s += __shfl_down(s, off);
    if ((t & 63) == 0) sred[t >> 6] = s;
    __syncthreads();
    double r = sred[0] + sred[1] + sred[2] + sred[3];
    __syncthreads();
    return r;
}

__global__ __launch_bounds__(256) void finalize_kernel(
    const double* __restrict__ attrP, const double* __restrict__ repgtP, int nA,
    const double* __restrict__ boxP, int nB,
    float* __restrict__ out, int N, long long cnt)
{
    __shared__ double sred[4];
    int t = threadIdx.x;
    double attr   = block_sum(attrP, nA, t, sred);
    double repgt  = block_sum(repgtP, nA, t, sred);
    double repbox = block_sum(boxP, nB, t, sred);
    if (t == 0) {
        out[0] = (float)(attr / (double)N + 0.5 * repgt / (double)N
                         + 0.5 * repbox / (double)cnt);
    }
}

extern "C" void kernel_launch(void* const* d_in, const int* in_sizes, int n_in,
                              void* d_out, int out_size, void* d_ws, size_t ws_size,
                              hipStream_t stream) {
    const float* gt  = (const float*)d_in[0];
    const float* pre = (const float*)d_in[1];
    int M = in_sizes[0] / 4;   // 512
    int N = in_sizes[1] / 4;   // 8192

    int nt = (N + 127) / 128;             // 64 tiles
    int nTri = nt * (nt + 1) / 2;         // 2080 upper-tri tile pairs
    const int ATTR_BLOCKS = 1024;
    const int BOX_BLOCKS  = 1024;

    char* ws = (char*)d_ws;
    size_t off = 0;
    double* attrP  = (double*)(ws + off); off += ((size_t)ATTR_BLOCKS * 8 + 255) / 256 * 256;
    double* repgtP = (double*)(ws + off); off += ((size_t)ATTR_BLOCKS * 8 + 255) / 256 * 256;
    double* boxP   = (double*)(ws + off); off += ((size_t)BOX_BLOCKS * 8 + 255) / 256 * 256;
    float*  gB     = (float*)(ws + off);  off += ((size_t)M * 8 * 4 + 255) / 256 * 256;
    float*  pB     = (float*)(ws + off);  off += ((size_t)N * 8 * 4 + 255) / 256 * 256;
    float*  sB     = (float*)(ws + off);  off += ((size_t)N * 8 * 4 + 255) / 256 * 256;
    int*    bucketId = (int*)(ws + off);  off += ((size_t)N * 4 + 255) / 256 * 256;
    float*  tb     = (float*)(ws + off);  off += ((size_t)nt * 2 * 4 + 255) / 256 * 256;
    float*  out    = (float*)d_out;

    int mx = (M > N) ? M : N;
    float bscale = (float)NBUCK / 640.0f;
    prep_kernel<<<(mx + 255) / 256, 256, 0, stream>>>(gt, pre, gB, pB, bucketId, M, N, bscale);

    sort_kernel<<<1, 1024, 0, stream>>>(pB, bucketId, sB, tb, N);

    attr_repgt_kernel<<<ATTR_BLOCKS, 256, 0, stream>>>(gB, pB, attrP, repgtP, M, N);

    repbox_kernel<<<BOX_BLOCKS, 256, 0, stream>>>(sB, tb, boxP, N, nt, nTri);

    long long cnt = (long long)N * (N - 1) / 2;
    finalize_kernel<<<1, 256, 0, stream>>>(attrP, repgtP, ATTR_BLOCKS, boxP, BOX_BLOCKS, out, N, cnt);
}

// Round 6
// 60.839 us; speedup vs baseline: 1.3946x; 1.3946x over previous
//
#include <hip/hip_runtime.h>
#include <math.h>

#define EPSF 1e-7f
// 1/(1 - SIGMA - ln(1 - SIGMA)) with SIGMA = 0.5
#define REP_INV (1.0f / 1.19314718055994530942f)
#define NBUCK 1024

// Box record: 8 floats (32B aligned): x0, y0, x1p(=x1+1), y1p(=y1+1), area(+1 conv), pad*3

// ---------------------------------------------------------------------------
// prep: xywh -> records; bucket id (x-center quantized) per pred.
// ---------------------------------------------------------------------------
__global__ __launch_bounds__(256) void prep_kernel(
    const float* __restrict__ gt, const float* __restrict__ pre,
    float* __restrict__ gB, float* __restrict__ pB, int* __restrict__ bucketId,
    int M, int N, float bscale)
{
    int i = blockIdx.x * 256 + threadIdx.x;
    if (i < M) {
        float x = gt[i * 4 + 0], y = gt[i * 4 + 1], w = gt[i * 4 + 2], h = gt[i * 4 + 3];
        float x0 = x - w * 0.5f, y0 = y - h * 0.5f;
        float x1p = x + w * 0.5f + 1.0f, y1p = y + h * 0.5f + 1.0f;
        *(float4*)(gB + (size_t)i * 8) = make_float4(x0, y0, x1p, y1p);
        gB[(size_t)i * 8 + 4] = (x1p - x0) * (y1p - y0);
    }
    if (i < N) {
        float x = pre[i * 4 + 0], y = pre[i * 4 + 1], w = pre[i * 4 + 2], h = pre[i * 4 + 3];
        float x0 = x - w * 0.5f, y0 = y - h * 0.5f;
        float x1p = x + w * 0.5f + 1.0f, y1p = y + h * 0.5f + 1.0f;
        *(float4*)(pB + (size_t)i * 8) = make_float4(x0, y0, x1p, y1p);
        pB[(size_t)i * 8 + 4] = (x1p - x0) * (y1p - y0);
        int b = (int)(x * bscale);
        bucketId[i] = min(max(b, 0), NBUCK - 1);
    }
}

// ---------------------------------------------------------------------------
// scanhist: ONE small block. Histogram of bucketIds + exclusive scan ->
// global cursors. (No data movement here; scatter is parallel.)
// ---------------------------------------------------------------------------
__global__ __launch_bounds__(1024) void scanhist_kernel(
    const int* __restrict__ bucketId, int* __restrict__ cursor, int N)
{
    __shared__ int hist[NBUCK];
    __shared__ int scanb[NBUCK];
    int t = threadIdx.x;
    hist[t] = 0;
    __syncthreads();
    int nc = (N + 1023) >> 10;
    for (int k = 0; k < nc; ++k) {
        int i = k * 1024 + t;
        if (i < N) atomicAdd(&hist[bucketId[i]], 1);
    }
    __syncthreads();
    int own = hist[t];
    scanb[t] = own;
    __syncthreads();
    for (int off = 1; off < NBUCK; off <<= 1) {
        int u = (t >= off) ? scanb[t - off] : 0;
        __syncthreads();
        scanb[t] += u;
        __syncthreads();
    }
    cursor[t] = scanb[t] - own;   // exclusive offset
}

// ---------------------------------------------------------------------------
// scatter: parallel counting-sort placement (within-bucket order is
// nondeterministic; pair-sum is permutation-invariant so result is exact
// up to FP summation order).
// ---------------------------------------------------------------------------
__global__ __launch_bounds__(256) void scatter_kernel(
    const float* __restrict__ pB, const int* __restrict__ bucketId,
    int* __restrict__ cursor, float* __restrict__ sB, int N)
{
    int i = blockIdx.x * 256 + threadIdx.x;
    if (i < N) {
        int dst = atomicAdd(&cursor[bucketId[i]], 1);
        float4 r = *(const float4*)(pB + (size_t)i * 8);
        float  a = pB[(size_t)i * 8 + 4];
        *(float4*)(sB + (size_t)dst * 8) = r;
        sB[(size_t)dst * 8 + 4] = a;
    }
}

// ---------------------------------------------------------------------------
// bounds: per-128-box tile x-interval [min x0, max x1p] of the sorted array.
// One block (128 threads, 2 waves) per tile.
// ---------------------------------------------------------------------------
__global__ __launch_bounds__(128) void bounds_kernel(
    const float* __restrict__ sB, float* __restrict__ tb, int N)
{
    __shared__ float wmin[2], wmax[2];
    int t = threadIdx.x;
    int i = blockIdx.x * 128 + t;
    float x0 = 3.4e38f, x1p = -3.4e38f;
    if (i < N) { x0 = sB[(size_t)i * 8]; x1p = sB[(size_t)i * 8 + 2]; }
    for (int off = 32; off > 0; off >>= 1) {
        x0  = fminf(x0,  __shfl_xor(x0, off));
        x1p = fmaxf(x1p, __shfl_xor(x1p, off));
    }
    if ((t & 63) == 0) { wmin[t >> 6] = x0; wmax[t >> 6] = x1p; }
    __syncthreads();
    if (t == 0) {
        tb[2 * blockIdx.x]     = fminf(wmin[0], wmin[1]);
        tb[2 * blockIdx.x + 1] = fmaxf(wmax[0], wmax[1]);
    }
}

// ---------------------------------------------------------------------------
// attr + repgt: ONE WAVE per prediction (round-4 version, unchanged).
// ---------------------------------------------------------------------------
__global__ __launch_bounds__(256) void attr_repgt_kernel(
    const float* __restrict__ gB, const float* __restrict__ pB,
    double* __restrict__ attrP, double* __restrict__ repgtP, int M, int N)
{
    __shared__ float4 gs4[512];
    __shared__ float  gsA[512];
    __shared__ double red[8];
    int t = threadIdx.x;
    for (int k = t; k < M; k += 256) {
        gs4[k] = *(const float4*)(gB + (size_t)k * 8);
        gsA[k] = gB[(size_t)k * 8 + 4];
    }
    if (t < 8) red[t] = 0.0;
    __syncthreads();

    int wave = t >> 6, lane = t & 63;
    int n = blockIdx.x * 4 + wave;
    if (n < N) {
        float4 p = *(const float4*)(pB + (size_t)n * 8);
        float  pa = pB[(size_t)n * 8 + 4];

        float best1 = -1.0f; int idx1 = 0;
        for (int m = lane; m < M; m += 64) {
            float4 g = gs4[m]; float ga = gsA[m];
            float w = fmaxf(fminf(g.z, p.z) - fmaxf(g.x, p.x), 0.0f);
            float h = fmaxf(fminf(g.w, p.w) - fmaxf(g.y, p.y), 0.0f);
            float ov = w * h;
            float v = ov * __builtin_amdgcn_rcpf(fmaxf(ga + pa - ov, EPSF));
            v = fminf(fmaxf(v, EPSF), 1.0f);
            if (v > best1) { best1 = v; idx1 = m; }
        }
        for (int off = 32; off > 0; off >>= 1) {
            float bv = __shfl_xor(best1, off);
            int   bi = __shfl_xor(idx1, off);
            if (bv > best1 || (bv == best1 && bi < idx1)) { best1 = bv; idx1 = bi; }
        }

        float best2 = -1.0f; int idx2 = 0;
        for (int m = lane; m < M; m += 64) {
            float4 g = gs4[m]; float ga = gsA[m];
            float w = fmaxf(fminf(g.z, p.z) - fmaxf(g.x, p.x), 0.0f);
            float h = fmaxf(fminf(g.w, p.w) - fmaxf(g.y, p.y), 0.0f);
            float ov = w * h;
            float v = ov * __builtin_amdgcn_rcpf(fmaxf(ga + pa - ov, EPSF));
            v = fminf(fmaxf(v, EPSF), 1.0f);
            v = (m == idx1) ? -1.0f : v;   // scatter-zero equivalent
            if (v > best2) { best2 = v; idx2 = m; }
        }
        for (int off = 32; off > 0; off >>= 1) {
            float bv = __shfl_xor(best2, off);
            int   bi = __shfl_xor(idx2, off);
            if (bv > best2 || (bv == best2 && bi < idx2)) { best2 = bv; idx2 = bi; }
        }

        // attr: smooth-l1 (beta=1) vs g[idx1]; (x1p - gx1p) == (x1 - gx1)
        float4 a = gs4[idx1];
        float s = 0.0f, d;
        d = fabsf(p.x - a.x); s += (d < 1.0f) ? 0.5f * d * d : d - 0.5f;
        d = fabsf(p.y - a.y); s += (d < 1.0f) ? 0.5f * d * d : d - 0.5f;
        d = fabsf(p.z - a.z); s += (d < 1.0f) ? 0.5f * d * d : d - 0.5f;
        d = fabsf(p.w - a.w); s += (d < 1.0f) ? 0.5f * d * d : d - 0.5f;

        // repgt: IoG (no +1 convention) vs g[idx2]; raw x1 = x1p - 1
        float4 rg = gs4[idx2];
        float lx = fmaxf(p.x, rg.x), ly = fmaxf(p.y, rg.y);
        float rbx = fminf(p.z, rg.z) - 1.0f, rby = fminf(p.w, rg.w) - 1.0f;
        float w = fmaxf(rbx - lx, 0.0f), h = fmaxf(rby - ly, 0.0f);
        float inter = w * h;
        float garea = fabsf(rg.z - 1.0f - rg.x) * fabsf(rg.w - 1.0f - rg.y);
        float iog = inter / garea;
        float rep;
        if (iog > 0.5f) rep = (iog - 0.5f) * REP_INV;
        else            rep = -logf(fmaxf(1.0f - iog, EPSF));

        if (lane == 0) { red[wave] = (double)s; red[4 + wave] = (double)rep; }
    }
    __syncthreads();
    if (t == 0) {
        attrP[blockIdx.x]  = red[0] + red[1] + red[2] + red[3];
        repgtP[blockIdx.x] = red[4] + red[5] + red[6] + red[7];
    }
}

// ---------------------------------------------------------------------------
// repbox (round-4 body on SORTED preds + uniform tile-skip): strict
// upper-tri 128x128 tiles, 1D triangular grid. Tiles with disjoint
// x-intervals contribute only dropped ~1e-7 eps terms -> skip (write 0).
// ---------------------------------------------------------------------------
__global__ __launch_bounds__(256) void repbox_kernel(
    const float* __restrict__ sB, const float* __restrict__ tb,
    double* __restrict__ boxP, int N, int nt)
{
    // decode triangular index s -> (bi, bj), bi <= bj
    int s = blockIdx.x;
    float a = 2.0f * (float)nt + 1.0f;
    int bi = (int)((a - sqrtf(a * a - 8.0f * (float)s)) * 0.5f);
    if (bi < 0) bi = 0;
    if (bi > nt - 1) bi = nt - 1;
    while (bi > 0 && (long long)bi * nt - (long long)bi * (bi - 1) / 2 > s) --bi;
    while ((long long)(bi + 1) * nt - (long long)(bi + 1) * bi / 2 <= s) ++bi;
    long long rowoff = (long long)bi * nt - (long long)bi * (bi - 1) / 2;
    int bj = bi + (int)(s - rowoff);

    int t = threadIdx.x;

    // x-disjoint tile skip (scalar, block-uniform)
    float rmin = tb[2 * bi], rmax = tb[2 * bi + 1];
    float cmin = tb[2 * bj], cmax = tb[2 * bj + 1];
    if (cmin >= rmax || rmin >= cmax) {
        if (t == 0) boxP[blockIdx.x] = 0.0;
        return;
    }

    __shared__ float4 rows4[128];
    __shared__ float  rowsA[128];
    __shared__ double red[4];
    int rbase = bi * 128, cbase = bj * 128;

    if (t < 128) {
        int rg = rbase + t;
        int rc = (rg < N) ? rg : 0;
        rows4[t] = *(const float4*)(sB + (size_t)rc * 8);
        rowsA[t] = sB[(size_t)rc * 8 + 4];
    }

    int wv = t >> 6, lane = t & 63;
    int j0 = cbase + lane, j1 = j0 + 64;
    int j0c = (j0 < N) ? j0 : 0;
    int j1c = (j1 < N) ? j1 : 0;
    float4 c0 = *(const float4*)(sB + (size_t)j0c * 8);
    float  c0a = sB[(size_t)j0c * 8 + 4];
    float4 c1 = *(const float4*)(sB + (size_t)j1c * 8);
    float  c1a = sB[(size_t)j1c * 8 + 4];
    __syncthreads();

    float sum = 0.0f;
    int r0 = wv * 32;
    bool interior = (bi < bj) && (rbase + 128 <= N) && (cbase + 128 <= N);

    if (interior) {
        #pragma unroll 4
        for (int rr = 0; rr < 32; ++rr) {
            int r = r0 + rr;
            float4 rb = rows4[r]; float ra = rowsA[r];
            float w0 = fmaxf(fminf(rb.z, c0.z) - fmaxf(rb.x, c0.x), 0.0f);
            float h0 = fmaxf(fminf(rb.w, c0.w) - fmaxf(rb.y, c0.y), 0.0f);
            float ov0 = w0 * h0;
            float w1 = fmaxf(fminf(rb.z, c1.z) - fmaxf(rb.x, c1.x), 0.0f);
            float h1 = fmaxf(fminf(rb.w, c1.w) - fmaxf(rb.y, c1.y), 0.0f);
            float ov1 = w1 * h1;
            if (__any(ov0 + ov1 > 0.0f)) {
                float v0 = ov0 * __builtin_amdgcn_rcpf(ra + c0a - ov0);
                float t0 = (v0 > 0.5f) ? (v0 - 0.5f) * REP_INV
                                       : 0.0f - __logf(fmaxf(1.0f - v0, EPSF));
                float v1 = ov1 * __builtin_amdgcn_rcpf(ra + c1a - ov1);
                float t1 = (v1 > 0.5f) ? (v1 - 0.5f) * REP_INV
                                       : 0.0f - __logf(fmaxf(1.0f - v1, EPSF));
                sum += t0 + t1;
            }
        }
    } else {
        #pragma unroll 4
        for (int rr = 0; rr < 32; ++rr) {
            int r = r0 + rr;
            int ig = rbase + r;
            float4 rb = rows4[r]; float ra = rowsA[r];
            float w0 = fmaxf(fminf(rb.z, c0.z) - fmaxf(rb.x, c0.x), 0.0f);
            float h0 = fmaxf(fminf(rb.w, c0.w) - fmaxf(rb.y, c0.y), 0.0f);
            float ov0 = w0 * h0;
            float w1 = fmaxf(fminf(rb.z, c1.z) - fmaxf(rb.x, c1.x), 0.0f);
            float h1 = fmaxf(fminf(rb.w, c1.w) - fmaxf(rb.y, c1.y), 0.0f);
            float ov1 = w1 * h1;
            bool valid0 = (j0 > ig) && (j0 < N) && (ig < N);
            bool valid1 = (j1 > ig) && (j1 < N) && (ig < N);
            if (__any(ov0 + ov1 > 0.0f)) {
                float v0 = ov0 * __builtin_amdgcn_rcpf(ra + c0a - ov0);
                float t0 = (v0 > 0.5f) ? (v0 - 0.5f) * REP_INV
                                       : 0.0f - __logf(fmaxf(1.0f - v0, EPSF));
                float v1 = ov1 * __builtin_amdgcn_rcpf(ra + c1a - ov1);
                float t1 = (v1 > 0.5f) ? (v1 - 0.5f) * REP_INV
                                       : 0.0f - __logf(fmaxf(1.0f - v1, EPSF));
                if (valid0) sum += t0;
                if (valid1) sum += t1;
            }
        }
    }

    for (int off = 32; off > 0; off >>= 1) sum += __shfl_down(sum, off);
    if (lane == 0) red[wv] = (double)sum;
    __syncthreads();
    if (t == 0) boxP[blockIdx.x] = red[0] + red[1] + red[2] + red[3];
}

// ---------------------------------------------------------------------------
// finalize: one block sums the partial arrays (L2-resident).
// ---------------------------------------------------------------------------
__device__ __forceinline__ double block_sum(const double* p, int n, int t,
                                            double* sred) {
    double s = 0.0;
    for (int k = t; k < n; k += 256) s += p[k];
    for (int off = 32; off > 0; off >>= 1) s += __shfl_down(s, off);
    if ((t & 63) == 0) sred[t >> 6] = s;
    __syncthreads();
    double r = sred[0] + sred[1] + sred[2] + sred[3];
    __syncthreads();
    return r;
}

__global__ __launch_bounds__(256) void finalize_kernel(
    const double* __restrict__ attrP, const double* __restrict__ repgtP, int nA,
    const double* __restrict__ boxP, int nB,
    float* __restrict__ out, int N, long long cnt)
{
    __shared__ double sred[4];
    int t = threadIdx.x;
    double attr   = block_sum(attrP, nA, t, sred);
    double repgt  = block_sum(repgtP, nA, t, sred);
    double repbox = block_sum(boxP, nB, t, sred);
    if (t == 0) {
        out[0] = (float)(attr / (double)N + 0.5 * repgt / (double)N
                         + 0.5 * repbox / (double)cnt);
    }
}

extern "C" void kernel_launch(void* const* d_in, const int* in_sizes, int n_in,
                              void* d_out, int out_size, void* d_ws, size_t ws_size,
                              hipStream_t stream) {
    const float* gt  = (const float*)d_in[0];
    const float* pre = (const float*)d_in[1];
    int M = in_sizes[0] / 4;   // 512
    int N = in_sizes[1] / 4;   // 8192

    int nblk_attr = (N + 3) / 4;          // 2048: one wave per prediction
    int nt = (N + 127) / 128;             // 64 tiles
    int nTri = nt * (nt + 1) / 2;         // 2080 upper-tri tile pairs

    char* ws = (char*)d_ws;
    size_t off = 0;
    double* attrP  = (double*)(ws + off); off += ((size_t)nblk_attr * 8 + 255) / 256 * 256;
    double* repgtP = (double*)(ws + off); off += ((size_t)nblk_attr * 8 + 255) / 256 * 256;
    double* boxP   = (double*)(ws + off); off += ((size_t)nTri * 8 + 255) / 256 * 256;
    float*  gB     = (float*)(ws + off);  off += ((size_t)M * 8 * 4 + 255) / 256 * 256;
    float*  pB     = (float*)(ws + off);  off += ((size_t)N * 8 * 4 + 255) / 256 * 256;
    float*  sB     = (float*)(ws + off);  off += ((size_t)N * 8 * 4 + 255) / 256 * 256;
    int*    bucketId = (int*)(ws + off);  off += ((size_t)N * 4 + 255) / 256 * 256;
    int*    cursor = (int*)(ws + off);    off += ((size_t)NBUCK * 4 + 255) / 256 * 256;
    float*  tb     = (float*)(ws + off);  off += ((size_t)nt * 2 * 4 + 255) / 256 * 256;
    float*  out    = (float*)d_out;

    int mx = (M > N) ? M : N;
    float bscale = (float)NBUCK / 640.0f;
    prep_kernel<<<(mx + 255) / 256, 256, 0, stream>>>(gt, pre, gB, pB, bucketId, M, N, bscale);

    scanhist_kernel<<<1, 1024, 0, stream>>>(bucketId, cursor, N);

    scatter_kernel<<<(N + 255) / 256, 256, 0, stream>>>(pB, bucketId, cursor, sB, N);

    bounds_kernel<<<nt, 128, 0, stream>>>(sB, tb, N);

    attr_repgt_kernel<<<nblk_attr, 256, 0, stream>>>(gB, pB, attrP, repgtP, M, N);

    repbox_kernel<<<nTri, 256, 0, stream>>>(sB, tb, boxP, N, nt);

    long long cnt = (long long)N * (N - 1) / 2;
    finalize_kernel<<<1, 256, 0, stream>>>(attrP, repgtP, nblk_attr, boxP, nTri, out, N, cnt);
}

// Round 7
// 44.090 us; speedup vs baseline: 1.9243x; 1.3799x over previous
//
#include <hip/hip_runtime.h>
#include <math.h>

#define EPSF 1e-7f
// 1/(1 - SIGMA - ln(1 - SIGMA)) with SIGMA = 0.5
#define REP_INV (1.0f / 1.19314718055994530942f)

// ---------------------------------------------------------------------------
// K1: fused repbox + attr/repgt. Grid = nTri + nAttr blocks, 256 threads.
//   bid < nTri               : repbox 128x128 upper-tri tile (bid = tri index)
//   bid >= nTri              : attr/repgt, one wave per prediction (4/block)
// All box records computed on the fly from raw xywh inputs (no prep pass).
// Per-block partial sums -> distinct ws slots (no atomics).
// ---------------------------------------------------------------------------
__global__ __launch_bounds__(256) void fused_kernel(
    const float* __restrict__ gt, const float* __restrict__ pre,
    double* __restrict__ boxP, double* __restrict__ attrP, double* __restrict__ repgtP,
    int M, int N, int nt, int nTri)
{
    __shared__ union {
        struct { float x0[512], y0[512], x1[512], y1[512], ar[512]; double red[8]; } a;
        struct { float4 rows4[128]; float rowsA[128]; double red[4]; } b;
    } sh;

    int t = threadIdx.x;
    int bid = blockIdx.x;
    int wv = t >> 6, lane = t & 63;

    if (bid < nTri) {
        // ================= repbox tile =================
        // decode triangular index -> (bi, bj), bi <= bj
        int s = bid;
        float aq = 2.0f * (float)nt + 1.0f;
        int bi = (int)((aq - sqrtf(aq * aq - 8.0f * (float)s)) * 0.5f);
        if (bi < 0) bi = 0;
        if (bi > nt - 1) bi = nt - 1;
        while (bi > 0 && (long long)bi * nt - (long long)bi * (bi - 1) / 2 > s) --bi;
        while ((long long)(bi + 1) * nt - (long long)(bi + 1) * bi / 2 <= s) ++bi;
        long long rowoff = (long long)bi * nt - (long long)bi * (bi - 1) / 2;
        int bj = bi + (int)(s - rowoff);

        int rbase = bi * 128, cbase = bj * 128;

        // stage row records (compute from raw pre)
        if (t < 128) {
            int rg = rbase + t;
            int rc = (rg < N) ? rg : 0;
            float4 q = *(const float4*)(pre + (size_t)rc * 4);  // x,y,w,h
            float x0 = q.x - q.z * 0.5f, y0 = q.y - q.w * 0.5f;
            float x1p = q.x + q.z * 0.5f + 1.0f, y1p = q.y + q.w * 0.5f + 1.0f;
            sh.b.rows4[t] = make_float4(x0, y0, x1p, y1p);
            sh.b.rowsA[t] = (x1p - x0) * (y1p - y0);
        }

        // column records in registers (2 per lane)
        int j0 = cbase + lane, j1 = j0 + 64;
        int j0c = (j0 < N) ? j0 : 0;
        int j1c = (j1 < N) ? j1 : 0;
        float4 q0 = *(const float4*)(pre + (size_t)j0c * 4);
        float4 q1 = *(const float4*)(pre + (size_t)j1c * 4);
        float c0x0 = q0.x - q0.z * 0.5f, c0y0 = q0.y - q0.w * 0.5f;
        float c0x1 = q0.x + q0.z * 0.5f + 1.0f, c0y1 = q0.y + q0.w * 0.5f + 1.0f;
        float c0a = (c0x1 - c0x0) * (c0y1 - c0y0);
        float c1x0 = q1.x - q1.z * 0.5f, c1y0 = q1.y - q1.w * 0.5f;
        float c1x1 = q1.x + q1.z * 0.5f + 1.0f, c1y1 = q1.y + q1.w * 0.5f + 1.0f;
        float c1a = (c1x1 - c1x0) * (c1y1 - c1y0);
        __syncthreads();

        float sum = 0.0f;
        int r0 = wv * 32;
        bool interior = (bi < bj) && (rbase + 128 <= N) && (cbase + 128 <= N);

        if (interior) {
            #pragma unroll 4
            for (int rr = 0; rr < 32; ++rr) {
                int r = r0 + rr;
                float4 rb = sh.b.rows4[r]; float ra = sh.b.rowsA[r];
                float w0 = fmaxf(fminf(rb.z, c0x1) - fmaxf(rb.x, c0x0), 0.0f);
                float h0 = fmaxf(fminf(rb.w, c0y1) - fmaxf(rb.y, c0y0), 0.0f);
                float ov0 = w0 * h0;
                float w1 = fmaxf(fminf(rb.z, c1x1) - fmaxf(rb.x, c1x0), 0.0f);
                float h1 = fmaxf(fminf(rb.w, c1y1) - fmaxf(rb.y, c1y0), 0.0f);
                float ov1 = w1 * h1;
                if (__any(ov0 + ov1 > 0.0f)) {
                    float v0 = ov0 * __builtin_amdgcn_rcpf(ra + c0a - ov0);
                    float t0 = (v0 > 0.5f) ? (v0 - 0.5f) * REP_INV
                                           : 0.0f - __logf(fmaxf(1.0f - v0, EPSF));
                    float v1 = ov1 * __builtin_amdgcn_rcpf(ra + c1a - ov1);
                    float t1 = (v1 > 0.5f) ? (v1 - 0.5f) * REP_INV
                                           : 0.0f - __logf(fmaxf(1.0f - v1, EPSF));
                    sum += t0 + t1;
                }
            }
        } else {
            #pragma unroll 4
            for (int rr = 0; rr < 32; ++rr) {
                int r = r0 + rr;
                int ig = rbase + r;
                float4 rb = sh.b.rows4[r]; float ra = sh.b.rowsA[r];
                float w0 = fmaxf(fminf(rb.z, c0x1) - fmaxf(rb.x, c0x0), 0.0f);
                float h0 = fmaxf(fminf(rb.w, c0y1) - fmaxf(rb.y, c0y0), 0.0f);
                float ov0 = w0 * h0;
                float w1 = fmaxf(fminf(rb.z, c1x1) - fmaxf(rb.x, c1x0), 0.0f);
                float h1 = fmaxf(fminf(rb.w, c1y1) - fmaxf(rb.y, c1y0), 0.0f);
                float ov1 = w1 * h1;
                bool valid0 = (j0 > ig) && (j0 < N) && (ig < N);
                bool valid1 = (j1 > ig) && (j1 < N) && (ig < N);
                if (__any(ov0 + ov1 > 0.0f)) {
                    float v0 = ov0 * __builtin_amdgcn_rcpf(ra + c0a - ov0);
                    float t0 = (v0 > 0.5f) ? (v0 - 0.5f) * REP_INV
                                           : 0.0f - __logf(fmaxf(1.0f - v0, EPSF));
                    float v1 = ov1 * __builtin_amdgcn_rcpf(ra + c1a - ov1);
                    float t1 = (v1 > 0.5f) ? (v1 - 0.5f) * REP_INV
                                           : 0.0f - __logf(fmaxf(1.0f - v1, EPSF));
                    if (valid0) sum += t0;
                    if (valid1) sum += t1;
                }
            }
        }

        for (int off = 32; off > 0; off >>= 1) sum += __shfl_down(sum, off);
        if (lane == 0) sh.b.red[wv] = (double)sum;
        __syncthreads();
        if (t == 0) boxP[bid] = sh.b.red[0] + sh.b.red[1] + sh.b.red[2] + sh.b.red[3];

    } else {
        // ================= attr + repgt =================
        int abid = bid - nTri;

        // stage gt records (SoA: stride-4B LDS reads -> 2-way aliasing, free)
        for (int k = t; k < M; k += 256) {
            float4 q = *(const float4*)(gt + (size_t)k * 4);  // x,y,w,h
            float x0 = q.x - q.z * 0.5f, y0 = q.y - q.w * 0.5f;
            float x1p = q.x + q.z * 0.5f + 1.0f, y1p = q.y + q.w * 0.5f + 1.0f;
            sh.a.x0[k] = x0; sh.a.y0[k] = y0;
            sh.a.x1[k] = x1p; sh.a.y1[k] = y1p;
            sh.a.ar[k] = (x1p - x0) * (y1p - y0);
        }
        if (t < 8) sh.a.red[t] = 0.0;
        __syncthreads();

        int n = abid * 4 + wv;
        if (n < N) {
            float4 q = *(const float4*)(pre + (size_t)n * 4);
            float px0 = q.x - q.z * 0.5f, py0 = q.y - q.w * 0.5f;
            float px1 = q.x + q.z * 0.5f + 1.0f, py1 = q.y + q.w * 0.5f + 1.0f;
            float pa = (px1 - px0) * (py1 - py0);

            float best1 = -1.0f; int idx1 = 0;
            for (int m = lane; m < M; m += 64) {
                float w = fmaxf(fminf(sh.a.x1[m], px1) - fmaxf(sh.a.x0[m], px0), 0.0f);
                float h = fmaxf(fminf(sh.a.y1[m], py1) - fmaxf(sh.a.y0[m], py0), 0.0f);
                float ov = w * h;
                float v = ov * __builtin_amdgcn_rcpf(fmaxf(sh.a.ar[m] + pa - ov, EPSF));
                v = fminf(fmaxf(v, EPSF), 1.0f);
                if (v > best1) { best1 = v; idx1 = m; }
            }
            for (int off = 32; off > 0; off >>= 1) {
                float bv = __shfl_xor(best1, off);
                int   bi2 = __shfl_xor(idx1, off);
                if (bv > best1 || (bv == best1 && bi2 < idx1)) { best1 = bv; idx1 = bi2; }
            }

            float best2 = -1.0f; int idx2 = 0;
            for (int m = lane; m < M; m += 64) {
                float w = fmaxf(fminf(sh.a.x1[m], px1) - fmaxf(sh.a.x0[m], px0), 0.0f);
                float h = fmaxf(fminf(sh.a.y1[m], py1) - fmaxf(sh.a.y0[m], py0), 0.0f);
                float ov = w * h;
                float v = ov * __builtin_amdgcn_rcpf(fmaxf(sh.a.ar[m] + pa - ov, EPSF));
                v = fminf(fmaxf(v, EPSF), 1.0f);
                v = (m == idx1) ? -1.0f : v;   // scatter-zero equivalent
                if (v > best2) { best2 = v; idx2 = m; }
            }
            for (int off = 32; off > 0; off >>= 1) {
                float bv = __shfl_xor(best2, off);
                int   bi2 = __shfl_xor(idx2, off);
                if (bv > best2 || (bv == best2 && bi2 < idx2)) { best2 = bv; idx2 = bi2; }
            }

            if (lane == 0) {
                // attr: smooth-l1 (beta=1) vs g[idx1]; (x1p - gx1p) == (x1 - gx1)
                float s = 0.0f, d;
                d = fabsf(px0 - sh.a.x0[idx1]); s += (d < 1.0f) ? 0.5f * d * d : d - 0.5f;
                d = fabsf(py0 - sh.a.y0[idx1]); s += (d < 1.0f) ? 0.5f * d * d : d - 0.5f;
                d = fabsf(px1 - sh.a.x1[idx1]); s += (d < 1.0f) ? 0.5f * d * d : d - 0.5f;
                d = fabsf(py1 - sh.a.y1[idx1]); s += (d < 1.0f) ? 0.5f * d * d : d - 0.5f;

                // repgt: IoG (no +1 convention) vs g[idx2]; raw x1 = x1p - 1
                float rx0 = sh.a.x0[idx2], ry0 = sh.a.y0[idx2];
                float rx1 = sh.a.x1[idx2] - 1.0f, ry1 = sh.a.y1[idx2] - 1.0f;
                float lx = fmaxf(px0, rx0), ly = fmaxf(py0, ry0);
                float rbx = fminf(px1 - 1.0f, rx1), rby = fminf(py1 - 1.0f, ry1);
                float w = fmaxf(rbx - lx, 0.0f), h = fmaxf(rby - ly, 0.0f);
                float inter = w * h;
                float garea = fabsf(rx1 - rx0) * fabsf(ry1 - ry0);
                float iog = inter / garea;
                float rep;
                if (iog > 0.5f) rep = (iog - 0.5f) * REP_INV;
                else            rep = -logf(fmaxf(1.0f - iog, EPSF));

                sh.a.red[wv] = (double)s;
                sh.a.red[4 + wv] = (double)rep;
            }
        }
        __syncthreads();
        if (t == 0) {
            attrP[abid]  = sh.a.red[0] + sh.a.red[1] + sh.a.red[2] + sh.a.red[3];
            repgtP[abid] = sh.a.red[4] + sh.a.red[5] + sh.a.red[6] + sh.a.red[7];
        }
    }
}

// ---------------------------------------------------------------------------
// K2: finalize — one block sums the partial arrays (L2-resident).
// ---------------------------------------------------------------------------
__device__ __forceinline__ double block_sum(const double* p, int n, int t,
                                            double* sred) {
    double s = 0.0;
    for (int k = t; k < n; k += 256) s += p[k];
    for (int off = 32; off > 0; off >>= 1) s += __shfl_down(s, off);
    if ((t & 63) == 0) sred[t >> 6] = s;
    __syncthreads();
    double r = sred[0] + sred[1] + sred[2] + sred[3];
    __syncthreads();
    return r;
}

__global__ __launch_bounds__(256) void finalize_kernel(
    const double* __restrict__ boxP, int nB,
    const double* __restrict__ attrP, const double* __restrict__ repgtP, int nA,
    float* __restrict__ out, int N, long long cnt)
{
    __shared__ double sred[4];
    int t = threadIdx.x;
    double repbox = block_sum(boxP, nB, t, sred);
    double attr   = block_sum(attrP, nA, t, sred);
    double repgt  = block_sum(repgtP, nA, t, sred);
    if (t == 0) {
        out[0] = (float)(attr / (double)N + 0.5 * repgt / (double)N
                         + 0.5 * repbox / (double)cnt);
    }
}

extern "C" void kernel_launch(void* const* d_in, const int* in_sizes, int n_in,
                              void* d_out, int out_size, void* d_ws, size_t ws_size,
                              hipStream_t stream) {
    const float* gt  = (const float*)d_in[0];
    const float* pre = (const float*)d_in[1];
    int M = in_sizes[0] / 4;   // 512
    int N = in_sizes[1] / 4;   // 8192

    int nA = (N + 3) / 4;                 // 2048 attr blocks (1 wave/pred)
    int nt = (N + 127) / 128;             // 64 tiles per dim
    int nTri = nt * (nt + 1) / 2;         // 2080 upper-tri tiles

    char* ws = (char*)d_ws;
    size_t off = 0;
    double* boxP   = (double*)(ws + off); off += ((size_t)nTri * 8 + 255) / 256 * 256;
    double* attrP  = (double*)(ws + off); off += ((size_t)nA * 8 + 255) / 256 * 256;
    double* repgtP = (double*)(ws + off);
    float*  out    = (float*)d_out;

    fused_kernel<<<nTri + nA, 256, 0, stream>>>(gt, pre, boxP, attrP, repgtP,
                                                M, N, nt, nTri);

    long long cnt = (long long)N * (N - 1) / 2;
    finalize_kernel<<<1, 256, 0, stream>>>(boxP, nTri, attrP, repgtP, nA, out, N, cnt);
}